// Round 3
// baseline (259.409 us; speedup 1.0000x reference)
//
#include <hip/hip_runtime.h>

// out[b] = SCALE^2 * ( dot(x[b,:], colsum) + sum(bias) ),  colsum[i] = sum_o W[o,i]
// Single fused kernel, 1024 co-resident blocks, 2 grid barriers.
//   Phase A: partial column sums of W (64 row-groups x 16 col-slices) + bias sum
//   Phase B: reduce 64 partials/column -> wsum (16 blocks, float4)
//   Phase C: matvec out = SCALE2*(x . wsum + bsum), 8 rows/block
// Barrier v2: hierarchical arrival (32 sub-counters -> master), load-only spin.

constexpr int IN_DIM = 2048;
constexpr int BATCH  = 8192;
constexpr float SCALE2 = 0.01f;   // SCALE*SCALE
constexpr int NB = 1024;          // 4 blocks/CU * 256 CU -> all co-resident

// Barrier memory layout (all zero-initialized by memsetAsync):
//   gen    at int offset 0    (own 64B line)
//   master at int offset 16   (own 64B line)
//   sub[i] at int offset 32 + i*16  (own 64B line each), i = 0..31
__device__ __forceinline__ void grid_barrier(int* bar, int sub_idx) {
    __syncthreads();
    if (threadIdx.x == 0) {
        __threadfence();  // release my global writes
        int* gen    = bar;
        int* master = bar + 16;
        int* sub    = bar + 32 + sub_idx * 16;

        const int g = __hip_atomic_load(gen, __ATOMIC_ACQUIRE,
                                        __HIP_MEMORY_SCOPE_AGENT);
        const int so = __hip_atomic_fetch_add(sub, 1, __ATOMIC_ACQ_REL,
                                              __HIP_MEMORY_SCOPE_AGENT);
        if (so == 31) {                       // last of this sub-group
            __hip_atomic_store(sub, 0, __ATOMIC_RELAXED,
                               __HIP_MEMORY_SCOPE_AGENT);
            __threadfence();                  // reset visible before master arrive
            const int mo = __hip_atomic_fetch_add(master, 1, __ATOMIC_ACQ_REL,
                                                  __HIP_MEMORY_SCOPE_AGENT);
            if (mo == 31) {                   // last sub-group overall
                __hip_atomic_store(master, 0, __ATOMIC_RELAXED,
                                   __HIP_MEMORY_SCOPE_AGENT);
                __threadfence();
                __hip_atomic_fetch_add(gen, 1, __ATOMIC_ACQ_REL,
                                       __HIP_MEMORY_SCOPE_AGENT);
            }
        }
        // load-only spin with backoff; bounded as watchdog
        for (long it = 0; it < (1L << 22); ++it) {
            if (__hip_atomic_load(gen, __ATOMIC_ACQUIRE,
                                  __HIP_MEMORY_SCOPE_AGENT) != g) break;
            __builtin_amdgcn_s_sleep(2);
        }
        __threadfence();  // acquire side
    }
    __syncthreads();
}

__global__ __launch_bounds__(256, 4)
void fused_kernel(const float* __restrict__ x, const float* __restrict__ W,
                  const float* __restrict__ bias, float* __restrict__ out,
                  int* bar, float* bsum, float* wsum, float* partial) {
    const int t    = threadIdx.x;
    const int b    = blockIdx.x;
    const int lane = t & 63;
    const int w    = t >> 6;
    const int sub_idx = b >> 5;  // 32 blocks per sub-counter

    __shared__ float4 redA[4][32];
    __shared__ float4 redB[256];
    __shared__ float  bs_red[4];

    // ---------------- Phase A: partial column sums of W ----------------
    {
        const int h  = b & 15;                       // col-slice: 128 cols
        const int g  = b >> 4;                       // row-group: 32 rows
        const int c4 = (h << 7) + ((t & 31) << 2);   // this thread's 4 cols
        const int r0 = (g << 5) + (t >> 5);          // first of 4 rows (stride 8)

        float4 acc = {0.f, 0.f, 0.f, 0.f};
        #pragma unroll
        for (int k = 0; k < 4; ++k) {
            const float4 v = *reinterpret_cast<const float4*>(
                W + (size_t)(r0 + 8 * k) * IN_DIM + c4);
            acc.x += v.x; acc.y += v.y; acc.z += v.z; acc.w += v.w;
        }
        // combine lanes (t, t^32): same cols, different row subset
        acc.x += __shfl_xor(acc.x, 32);
        acc.y += __shfl_xor(acc.y, 32);
        acc.z += __shfl_xor(acc.z, 32);
        acc.w += __shfl_xor(acc.w, 32);
        if (lane < 32) redA[w][lane] = acc;
        __syncthreads();
        if (w == 0 && lane < 32) {
            float4 a = redA[0][lane], b1 = redA[1][lane],
                   c = redA[2][lane], d = redA[3][lane];
            float4 s = { a.x + b1.x + c.x + d.x,
                         a.y + b1.y + c.y + d.y,
                         a.z + b1.z + c.z + d.z,
                         a.w + b1.w + c.w + d.w };
            *reinterpret_cast<float4*>(partial + (size_t)g * IN_DIM + c4) = s;
        }
    }

    // block NB-1 additionally reduces the bias vector
    if (b == NB - 1) {
        float s = 0.f;
        #pragma unroll
        for (int k = 0; k < 8; ++k) s += bias[t + (k << 8)];
        #pragma unroll
        for (int off = 32; off; off >>= 1) s += __shfl_down(s, off);
        if (lane == 0) bs_red[w] = s;
        __syncthreads();
        if (t == 0) bsum[0] = bs_red[0] + bs_red[1] + bs_red[2] + bs_red[3];
    }

    grid_barrier(bar, sub_idx);

    // ---------------- Phase B: reduce partials -> wsum (16 blocks) -------
    if (b < 16) {
        const float4* p4 = reinterpret_cast<const float4*>(partial);
        const int base4 = (b << 5) + (t & 31);       // float4 col index 0..511
        const int g0 = (t >> 5) << 3;                // 8 groups per thread
        float4 s = {0.f, 0.f, 0.f, 0.f};
        #pragma unroll
        for (int k = 0; k < 8; ++k) {
            const float4 v = p4[(size_t)(g0 + k) * (IN_DIM / 4) + base4];
            s.x += v.x; s.y += v.y; s.z += v.z; s.w += v.w;
        }
        redB[t] = s;
        __syncthreads();
        if (t < 32) {
            float4 a = redB[t];
            #pragma unroll
            for (int j = 1; j < 8; ++j) {
                const float4 v = redB[t + (j << 5)];
                a.x += v.x; a.y += v.y; a.z += v.z; a.w += v.w;
            }
            reinterpret_cast<float4*>(wsum)[(b << 5) + t] = a;
        }
    }

    grid_barrier(bar, sub_idx);

    // ---------------- Phase C: matvec ----------------
    {
        const float bs = bsum[0];
        const int r0 = (b << 3) + (w << 1);          // 2 rows per wave
        const int r1 = r0 + 1;
        const float4* x4 = reinterpret_cast<const float4*>(x);
        const float4* w4 = reinterpret_cast<const float4*>(wsum);

        float a0 = 0.f, a1 = 0.f;
        #pragma unroll
        for (int k = 0; k < 8; ++k) {
            const float4 wv = w4[(k << 6) + lane];
            const float4 v0 = x4[(size_t)r0 * (IN_DIM / 4) + (k << 6) + lane];
            const float4 v1 = x4[(size_t)r1 * (IN_DIM / 4) + (k << 6) + lane];
            a0 += v0.x * wv.x + v0.y * wv.y + v0.z * wv.z + v0.w * wv.w;
            a1 += v1.x * wv.x + v1.y * wv.y + v1.z * wv.z + v1.w * wv.w;
        }
        #pragma unroll
        for (int off = 32; off; off >>= 1) {
            a0 += __shfl_down(a0, off);
            a1 += __shfl_down(a1, off);
        }
        if (lane == 0) {
            out[r0] = SCALE2 * (a0 + bs);
            out[r1] = SCALE2 * (a1 + bs);
        }
    }
}

extern "C" void kernel_launch(void* const* d_in, const int* in_sizes, int n_in,
                              void* d_out, int out_size, void* d_ws, size_t ws_size,
                              hipStream_t stream) {
    const float* x    = (const float*)d_in[0];   // [8192, 2048]
    const float* W    = (const float*)d_in[1];   // [2048, 2048]
    const float* bias = (const float*)d_in[2];   // [2048]
    float* out = (float*)d_out;                  // [8192]
    char*  ws  = (char*)d_ws;

    // ws layout: [0, 4K)       barrier (gen/master/32 sub-counters, 64B apart)
    //            [4K, 4K+64)   bsum
    //            [4K+64, +8K)  wsum[2048]
    //            then          partial[64][2048]  (512 KB)
    int*   bar     = (int*)ws;
    float* bsum    = (float*)(ws + 4096);
    float* wsum    = (float*)(ws + 4096 + 64);
    float* partial = (float*)(ws + 4096 + 64 + IN_DIM * sizeof(float));

    hipMemsetAsync(bar, 0, 4096, stream);
    fused_kernel<<<NB, 256, 0, stream>>>(x, W, bias, out, bar, bsum, wsum, partial);
}

// Round 5
// 31.571 us; speedup vs baseline: 8.2167x; 8.2167x over previous
//
#include <hip/hip_runtime.h>

// out[b] = SCALE^2 * ( dot(x[b,:], colsum) + sum(bias) ),  colsum[i] = sum_o W[o,i]
// Two plain kernels, no atomics / barriers / memsets / spins:
//   K1: partial[g][c] = sum of W rows [32g,32g+32) for col c   (256 blocks)
//       block 0 also writes bsum = sum(bias)
//   K2: each block redundantly reduces partial -> wsum in LDS (L2-resident),
//       then matvec for its 32 rows: out = SCALE2*(x.wsum + bsum)
// Cross-kernel visibility via the runtime's end-of-kernel L2 writeback.

constexpr int IN_DIM  = 2048;
constexpr int BATCH   = 8192;
constexpr float SCALE2 = 0.01f;   // SCALE*SCALE
constexpr int DGROUPS = 64;       // partial depth (32 rows each)

// ---------------------------------------------------------------------------
// K1: 256 blocks x 256 threads. Block b: row-group g = b>>2 (32 rows),
// col-slice h = b&3 (512 cols). Each thread owns one float2 (2 cols).
// ---------------------------------------------------------------------------
__global__ __launch_bounds__(256)
void colsum_partial(const float* __restrict__ W, const float* __restrict__ bias,
                    float* __restrict__ partial, float* __restrict__ bsum) {
    const int t = threadIdx.x;
    const int b = blockIdx.x;
    const int g = b >> 2;
    const int h = b & 3;

    const float2* W2 = reinterpret_cast<const float2*>(W);
    const int c2 = (h << 8) + t;                       // float2 col index 0..1023
    const size_t base = (size_t)(g << 5) * (IN_DIM / 2) + c2;

    float2 acc = {0.f, 0.f};
    #pragma unroll 8
    for (int r = 0; r < 32; ++r) {
        const float2 v = W2[base + (size_t)r * (IN_DIM / 2)];
        acc.x += v.x; acc.y += v.y;
    }
    reinterpret_cast<float2*>(partial)[(size_t)g * (IN_DIM / 2) + c2] = acc;

    if (b == 0) {  // bias sum (runs concurrently with other blocks)
        __shared__ float bs_red[4];
        const int lane = t & 63, w = t >> 6;
        float s = 0.f;
        #pragma unroll
        for (int k = 0; k < 8; ++k) s += bias[t + (k << 8)];
        #pragma unroll
        for (int off = 32; off; off >>= 1) s += __shfl_down(s, off);
        if (lane == 0) bs_red[w] = s;
        __syncthreads();
        if (t == 0) bsum[0] = bs_red[0] + bs_red[1] + bs_red[2] + bs_red[3];
    }
}

// ---------------------------------------------------------------------------
// K2: 256 blocks x 512 threads (8 waves). Phase 1: reduce partial (512 KB,
// L2-resident) into LDS wsum. Phase 2: matvec for rows [32b, 32b+32);
// wave w handles rows 32b + 4w .. +3, all four accumulated in one k-loop.
// ---------------------------------------------------------------------------
__global__ __launch_bounds__(512)
void reduce_matvec(const float* __restrict__ x, const float* __restrict__ partial,
                   const float* __restrict__ bsum, float* __restrict__ out) {
    __shared__ float4 wsh4[IN_DIM / 4];   // 8 KB
    __shared__ float  bs_sh;

    const int t    = threadIdx.x;          // 0..511
    const int b    = blockIdx.x;           // 0..255
    const int lane = t & 63;
    const int w    = t >> 6;               // 0..7

    // ---- Phase 1: wsum = sum_g partial[g][*]  (thread t owns float4 col t)
    const float4* p4 = reinterpret_cast<const float4*>(partial);
    float4 acc = {0.f, 0.f, 0.f, 0.f};
    #pragma unroll 8
    for (int i = 0; i < DGROUPS; ++i) {
        const int g = (i + b) & (DGROUPS - 1);   // stagger start per block
        const float4 v = p4[(size_t)g * (IN_DIM / 4) + t];
        acc.x += v.x; acc.y += v.y; acc.z += v.z; acc.w += v.w;
    }
    wsh4[t] = acc;
    if (t == 0) bs_sh = bsum[0];
    __syncthreads();

    // ---- Phase 2: matvec, 4 rows per wave
    const float4* x4 = reinterpret_cast<const float4*>(x);
    const int r0 = (b << 5) + (w << 2);
    const size_t xb = (size_t)r0 * (IN_DIM / 4);

    float a0 = 0.f, a1 = 0.f, a2 = 0.f, a3 = 0.f;
    #pragma unroll
    for (int k = 0; k < 8; ++k) {
        const int ci = (k << 6) + lane;
        const float4 wv = wsh4[ci];
        const float4 v0 = x4[xb + ci];
        const float4 v1 = x4[xb + 512 + ci];
        const float4 v2 = x4[xb + 1024 + ci];
        const float4 v3 = x4[xb + 1536 + ci];
        a0 += v0.x * wv.x + v0.y * wv.y + v0.z * wv.z + v0.w * wv.w;
        a1 += v1.x * wv.x + v1.y * wv.y + v1.z * wv.z + v1.w * wv.w;
        a2 += v2.x * wv.x + v2.y * wv.y + v2.z * wv.z + v2.w * wv.w;
        a3 += v3.x * wv.x + v3.y * wv.y + v3.z * wv.z + v3.w * wv.w;
    }
    #pragma unroll
    for (int off = 32; off; off >>= 1) {
        a0 += __shfl_down(a0, off);
        a1 += __shfl_down(a1, off);
        a2 += __shfl_down(a2, off);
        a3 += __shfl_down(a3, off);
    }
    if (lane == 0) {
        const float bs = bs_sh;
        *reinterpret_cast<float4*>(out + r0) =
            make_float4(SCALE2 * (a0 + bs), SCALE2 * (a1 + bs),
                        SCALE2 * (a2 + bs), SCALE2 * (a3 + bs));
    }
}

extern "C" void kernel_launch(void* const* d_in, const int* in_sizes, int n_in,
                              void* d_out, int out_size, void* d_ws, size_t ws_size,
                              hipStream_t stream) {
    const float* x    = (const float*)d_in[0];   // [8192, 2048]
    const float* W    = (const float*)d_in[1];   // [2048, 2048]
    const float* bias = (const float*)d_in[2];   // [2048]
    float* out = (float*)d_out;                  // [8192]
    char*  ws  = (char*)d_ws;

    // ws layout: partial[64][2048] (512 KB) | bsum (64 B)
    float* partial = (float*)ws;
    float* bsum    = (float*)(ws + (size_t)DGROUPS * IN_DIM * sizeof(float));

    colsum_partial<<<256, 256, 0, stream>>>(W, bias, partial, bsum);
    reduce_matvec<<<BATCH / 32, 512, 0, stream>>>(x, partial, bsum, out);
}

// Round 6
// 27.873 us; speedup vs baseline: 9.3068x; 1.1327x over previous
//
#include <hip/hip_runtime.h>

// out[b] = SCALE^2 * ( dot(x[b,:], colsum) + sum(bias) ),  colsum[i] = sum_o W[o,i]
// Two plain kernels, no atomics / barriers / memsets / spins:
//   K1: partial[g][c] = sum of W rows [256g, 256g+256) for col c  (8 groups,
//       32 col-slices -> 256 blocks). Block 0 also writes bsum = sum(bias).
//   K2: each block redundantly reduces partial[8][2048] (64 KB, L2/L3-hot)
//       into LDS, then matvec for its 32 rows: out = SCALE2*(x.wsum + bsum)
// Cross-kernel visibility via the runtime's end-of-kernel L2 writeback.

constexpr int IN_DIM  = 2048;
constexpr int BATCH   = 8192;
constexpr float SCALE2 = 0.01f;   // SCALE*SCALE
constexpr int DGROUPS = 8;        // partial depth (256 rows each)

// ---------------------------------------------------------------------------
// K1: 256 blocks x 256 threads. Block b: row-group g = b>>5 (256 rows),
// col-slice h = b&31 (64 cols = 16 float4). Thread t: col4 = h*16 + (t&15),
// rows rsub + 16k for rsub = t>>4, k = 0..15. Reduce over rsub via
// shfl_xor(16,32) + LDS across the 4 waves.
// ---------------------------------------------------------------------------
__global__ __launch_bounds__(256)
void colsum_partial(const float* __restrict__ W, const float* __restrict__ bias,
                    float* __restrict__ partial, float* __restrict__ bsum) {
    const int t = threadIdx.x;
    const int b = blockIdx.x;
    const int g = b >> 5;
    const int h = b & 31;

    const float4* W4 = reinterpret_cast<const float4*>(W);
    const int c4   = (h << 4) + (t & 15);        // float4 col 0..511
    const int rsub = t >> 4;                     // 0..15
    const size_t base = (size_t)((g << 8) + rsub) * (IN_DIM / 4) + c4;

    float4 acc = {0.f, 0.f, 0.f, 0.f};
    #pragma unroll 4
    for (int k = 0; k < 16; ++k) {
        const float4 v = W4[base + (size_t)(k << 4) * (IN_DIM / 4)];
        acc.x += v.x; acc.y += v.y; acc.z += v.z; acc.w += v.w;
    }
    // merge rsub bits 0,1 (lanes t^16, t^32 share c4)
    acc.x += __shfl_xor(acc.x, 16); acc.y += __shfl_xor(acc.y, 16);
    acc.z += __shfl_xor(acc.z, 16); acc.w += __shfl_xor(acc.w, 16);
    acc.x += __shfl_xor(acc.x, 32); acc.y += __shfl_xor(acc.y, 32);
    acc.z += __shfl_xor(acc.z, 32); acc.w += __shfl_xor(acc.w, 32);

    __shared__ float4 redA[4][16];
    const int lane = t & 63, w = t >> 6;
    if (lane < 16) redA[w][lane] = acc;
    __syncthreads();
    if (w == 0 && lane < 16) {
        const float4 a = redA[0][lane], b1 = redA[1][lane],
                     c = redA[2][lane], d = redA[3][lane];
        reinterpret_cast<float4*>(partial)[(size_t)g * (IN_DIM / 4) + c4] =
            make_float4(a.x + b1.x + c.x + d.x, a.y + b1.y + c.y + d.y,
                        a.z + b1.z + c.z + d.z, a.w + b1.w + c.w + d.w);
    }

    if (b == 0) {  // bias sum (concurrent with the rest)
        __shared__ float bs_red[4];
        float s = 0.f;
        #pragma unroll
        for (int k = 0; k < 8; ++k) s += bias[t + (k << 8)];
        #pragma unroll
        for (int off = 32; off; off >>= 1) s += __shfl_down(s, off);
        if (lane == 0) bs_red[w] = s;
        __syncthreads();
        if (t == 0) bsum[0] = bs_red[0] + bs_red[1] + bs_red[2] + bs_red[3];
    }
}

// ---------------------------------------------------------------------------
// K2: 256 blocks x 512 threads (8 waves). Phase 1: reduce partial[8][2048]
// (64 KB, cache-hot) into LDS wsum. Phase 2: matvec for rows [32b, 32b+32);
// wave w handles rows 32b+4w.., 4 rows accumulated in one k-loop.
// ---------------------------------------------------------------------------
__global__ __launch_bounds__(512)
void reduce_matvec(const float* __restrict__ x, const float* __restrict__ partial,
                   const float* __restrict__ bsum, float* __restrict__ out) {
    __shared__ float4 wsh4[IN_DIM / 4];   // 8 KB
    __shared__ float  bs_sh;

    const int t    = threadIdx.x;          // 0..511
    const int b    = blockIdx.x;           // 0..255
    const int lane = t & 63;
    const int w    = t >> 6;               // 0..7

    // ---- Phase 1: wsum = sum_g partial[g][*]  (thread t owns float4 col t)
    const float4* p4 = reinterpret_cast<const float4*>(partial);
    float4 acc = {0.f, 0.f, 0.f, 0.f};
    #pragma unroll
    for (int i = 0; i < DGROUPS; ++i) {
        const int g = (i + b) & (DGROUPS - 1);   // stagger start per block
        const float4 v = p4[(size_t)g * (IN_DIM / 4) + t];
        acc.x += v.x; acc.y += v.y; acc.z += v.z; acc.w += v.w;
    }
    wsh4[t] = acc;
    if (t == 0) bs_sh = bsum[0];
    __syncthreads();

    // ---- Phase 2: matvec, 4 rows per wave
    const float4* x4 = reinterpret_cast<const float4*>(x);
    const int r0 = (b << 5) + (w << 2);
    const size_t xb = (size_t)r0 * (IN_DIM / 4);

    float a0 = 0.f, a1 = 0.f, a2 = 0.f, a3 = 0.f;
    #pragma unroll
    for (int k = 0; k < 8; ++k) {
        const int ci = (k << 6) + lane;
        const float4 wv = wsh4[ci];
        const float4 v0 = x4[xb + ci];
        const float4 v1 = x4[xb + 512 + ci];
        const float4 v2 = x4[xb + 1024 + ci];
        const float4 v3 = x4[xb + 1536 + ci];
        a0 += v0.x * wv.x + v0.y * wv.y + v0.z * wv.z + v0.w * wv.w;
        a1 += v1.x * wv.x + v1.y * wv.y + v1.z * wv.z + v1.w * wv.w;
        a2 += v2.x * wv.x + v2.y * wv.y + v2.z * wv.z + v2.w * wv.w;
        a3 += v3.x * wv.x + v3.y * wv.y + v3.z * wv.z + v3.w * wv.w;
    }
    #pragma unroll
    for (int off = 32; off; off >>= 1) {
        a0 += __shfl_down(a0, off);
        a1 += __shfl_down(a1, off);
        a2 += __shfl_down(a2, off);
        a3 += __shfl_down(a3, off);
    }
    if (lane == 0) {
        const float bs = bs_sh;
        *reinterpret_cast<float4*>(out + r0) =
            make_float4(SCALE2 * (a0 + bs), SCALE2 * (a1 + bs),
                        SCALE2 * (a2 + bs), SCALE2 * (a3 + bs));
    }
}

extern "C" void kernel_launch(void* const* d_in, const int* in_sizes, int n_in,
                              void* d_out, int out_size, void* d_ws, size_t ws_size,
                              hipStream_t stream) {
    const float* x    = (const float*)d_in[0];   // [8192, 2048]
    const float* W    = (const float*)d_in[1];   // [2048, 2048]
    const float* bias = (const float*)d_in[2];   // [2048]
    float* out = (float*)d_out;                  // [8192]
    char*  ws  = (char*)d_ws;

    // ws layout: partial[8][2048] (64 KB) | bsum (64 B)
    float* partial = (float*)ws;
    float* bsum    = (float*)(ws + (size_t)DGROUPS * IN_DIM * sizeof(float));

    colsum_partial<<<256, 256, 0, stream>>>(W, bias, partial, bsum);
    reduce_matvec<<<BATCH / 32, 512, 0, stream>>>(x, partial, bsum, out);
}

// Round 7
// 22.987 us; speedup vs baseline: 11.2850x; 1.2126x over previous
//
#include <hip/hip_runtime.h>

// out[b] = SCALE^2 * ( dot(x[b,:], colsum) + sum(bias) ),  colsum[i] = sum_o W[o,i]
// Two plain kernels, no atomics / barriers / memsets / spins:
//   K1: partial[g][c] = sum of W rows [256g, 256g+256) for col c
//       (8 row-groups x 64 col-slices -> 512 blocks x 512 thr, 4 waves/SIMD).
//       Block 0 also writes bsum = sum(bias).
//   K2: 512 blocks x 512 thr; each block reduces partial[8][2048] (64 KB,
//       L2-hot) into LDS, then matvec for its 16 rows (2 rows/wave).
// Cross-kernel visibility via the runtime's end-of-kernel L2 writeback.

constexpr int IN_DIM  = 2048;
constexpr int BATCH   = 8192;
constexpr float SCALE2 = 0.01f;   // SCALE*SCALE
constexpr int DGROUPS = 8;        // partial depth (256 rows each)

// ---------------------------------------------------------------------------
// K1: 512 blocks x 512 threads. Block b: row-group g = b>>6 (256 rows),
// col-slice h = b&63 (32 cols = 8 float4). Thread t: col4 = h*8 + (t&7),
// rsub = t>>3 (0..63), rows g*256 + rsub + 64k, k = 0..3.
// Coalescing: 8 lanes x 16B = 128B contiguous per row segment.
// ---------------------------------------------------------------------------
__global__ __launch_bounds__(512)
void colsum_partial(const float* __restrict__ W, const float* __restrict__ bias,
                    float* __restrict__ partial, float* __restrict__ bsum) {
    const int t = threadIdx.x;          // 0..511
    const int b = blockIdx.x;           // 0..511
    const int g = b >> 6;               // 0..7
    const int h = b & 63;               // 0..63
    const int lane = t & 63, w = t >> 6;

    const float4* W4 = reinterpret_cast<const float4*>(W);
    const int c4   = (h << 3) + (t & 7);           // float4 col 0..511
    const int rsub = t >> 3;                       // 0..63
    const size_t base = (size_t)((g << 8) + rsub) * (IN_DIM / 4) + c4;

    float4 acc = {0.f, 0.f, 0.f, 0.f};
    #pragma unroll
    for (int k = 0; k < 4; ++k) {
        const float4 v = W4[base + (size_t)(k << 6) * (IN_DIM / 4)];
        acc.x += v.x; acc.y += v.y; acc.z += v.z; acc.w += v.w;
    }
    // merge rsub bits within the wave (lane bits 3,4,5); c4 invariant
    #pragma unroll
    for (int m = 8; m <= 32; m <<= 1) {
        acc.x += __shfl_xor(acc.x, m); acc.y += __shfl_xor(acc.y, m);
        acc.z += __shfl_xor(acc.z, m); acc.w += __shfl_xor(acc.w, m);
    }

    __shared__ float4 redA[8][8];       // [wave][col4 within slice]
    if (lane < 8) redA[w][lane] = acc;
    __syncthreads();
    if (t < 8) {                        // one thread per col4 of this slice
        float4 s = redA[0][t];
        #pragma unroll
        for (int j = 1; j < 8; ++j) {
            const float4 v = redA[j][t];
            s.x += v.x; s.y += v.y; s.z += v.z; s.w += v.w;
        }
        reinterpret_cast<float4*>(partial)[(size_t)g * (IN_DIM / 4) + (h << 3) + t] = s;
    }

    if (b == 0) {  // bias sum (concurrent with the rest)
        __shared__ float bs_red[8];
        float s = 0.f;
        #pragma unroll
        for (int k = 0; k < 4; ++k) s += bias[t + (k << 9)];
        #pragma unroll
        for (int off = 32; off; off >>= 1) s += __shfl_down(s, off);
        if (lane == 0) bs_red[w] = s;
        __syncthreads();
        if (t == 0) {
            float tot = 0.f;
            #pragma unroll
            for (int j = 0; j < 8; ++j) tot += bs_red[j];
            bsum[0] = tot;
        }
    }
}

// ---------------------------------------------------------------------------
// K2: 512 blocks x 512 threads (8 waves, 2 blocks/CU -> 4 waves/SIMD).
// Phase 1: reduce partial[8][2048] (64 KB, cache-hot) into LDS wsum.
// Phase 2: matvec for rows [16b, 16b+16); wave w rows 16b+2w, 16b+2w+1.
// ---------------------------------------------------------------------------
__global__ __launch_bounds__(512)
void reduce_matvec(const float* __restrict__ x, const float* __restrict__ partial,
                   const float* __restrict__ bsum, float* __restrict__ out) {
    __shared__ float4 wsh4[IN_DIM / 4];   // 8 KB
    __shared__ float  bs_sh;

    const int t    = threadIdx.x;          // 0..511
    const int b    = blockIdx.x;           // 0..511
    const int lane = t & 63;
    const int w    = t >> 6;               // 0..7

    // ---- Phase 1: wsum = sum_g partial[g][*]  (thread t owns float4 col t)
    const float4* p4 = reinterpret_cast<const float4*>(partial);
    float4 acc = {0.f, 0.f, 0.f, 0.f};
    #pragma unroll
    for (int i = 0; i < DGROUPS; ++i) {
        const int g = (i + b) & (DGROUPS - 1);   // stagger start per block
        const float4 v = p4[(size_t)g * (IN_DIM / 4) + t];
        acc.x += v.x; acc.y += v.y; acc.z += v.z; acc.w += v.w;
    }
    wsh4[t] = acc;
    if (t == 0) bs_sh = bsum[0];
    __syncthreads();

    // ---- Phase 2: matvec, 2 rows per wave
    const float4* x4 = reinterpret_cast<const float4*>(x);
    const int r0 = (b << 4) + (w << 1);
    const size_t xb = (size_t)r0 * (IN_DIM / 4);

    float a0 = 0.f, a1 = 0.f;
    #pragma unroll
    for (int k = 0; k < 8; ++k) {
        const int ci = (k << 6) + lane;
        const float4 wv = wsh4[ci];
        const float4 v0 = x4[xb + ci];
        const float4 v1 = x4[xb + 512 + ci];
        a0 += v0.x * wv.x + v0.y * wv.y + v0.z * wv.z + v0.w * wv.w;
        a1 += v1.x * wv.x + v1.y * wv.y + v1.z * wv.z + v1.w * wv.w;
    }
    #pragma unroll
    for (int off = 32; off; off >>= 1) {
        a0 += __shfl_down(a0, off);
        a1 += __shfl_down(a1, off);
    }
    if (lane == 0) {
        const float bs = bs_sh;
        out[r0]     = SCALE2 * (a0 + bs);
        out[r0 + 1] = SCALE2 * (a1 + bs);
    }
}

extern "C" void kernel_launch(void* const* d_in, const int* in_sizes, int n_in,
                              void* d_out, int out_size, void* d_ws, size_t ws_size,
                              hipStream_t stream) {
    const float* x    = (const float*)d_in[0];   // [8192, 2048]
    const float* W    = (const float*)d_in[1];   // [2048, 2048]
    const float* bias = (const float*)d_in[2];   // [2048]
    float* out = (float*)d_out;                  // [8192]
    char*  ws  = (char*)d_ws;

    // ws layout: partial[8][2048] (64 KB) | bsum (64 B)
    float* partial = (float*)ws;
    float* bsum    = (float*)(ws + (size_t)DGROUPS * IN_DIM * sizeof(float));

    colsum_partial<<<512, 512, 0, stream>>>(W, bias, partial, bsum);
    reduce_matvec<<<BATCH / 16, 512, 0, stream>>>(x, partial, bsum, out);
}

// Round 8
// 21.353 us; speedup vs baseline: 12.1488x; 1.0765x over previous
//
#include <hip/hip_runtime.h>

// out[b] = SCALE^2 * ( dot(x[b,:], colsum) + sum(bias) ),  colsum[i] = sum_o W[o,i]
// Two plain kernels, no atomics / barriers / memsets / spins:
//   K1: partial[g][c] = sum of W rows [256g, 256g+256) for col c
//       (8 row-groups x 64 col-slices -> 512 blocks x 512 thr, 4 waves/SIMD).
//       Block 0 also writes bsum = sum(bias).
//   K2: 512 blocks x 512 thr; each block reduces partial[8][2048] (64 KB,
//       L2-hot) into LDS, then matvec for its 16 rows (2 rows/wave).
//       Row-0 x loads are issued BEFORE the barrier so phase 1 hides them.
// Cross-kernel visibility via the runtime's end-of-kernel L2 writeback.

constexpr int IN_DIM  = 2048;
constexpr int BATCH   = 8192;
constexpr float SCALE2 = 0.01f;   // SCALE*SCALE
constexpr int DGROUPS = 8;        // partial depth (256 rows each)

// ---------------------------------------------------------------------------
// K1: 512 blocks x 512 threads. Block b: row-group g = b>>6 (256 rows),
// col-slice h = b&63 (32 cols = 8 float4). Thread t: col4 = h*8 + (t&7),
// rsub = t>>3 (0..63), rows g*256 + rsub + 64k, k = 0..3.
// Coalescing: 8 lanes x 16B = 128B contiguous per row segment.
// ---------------------------------------------------------------------------
__global__ __launch_bounds__(512)
void colsum_partial(const float* __restrict__ W, const float* __restrict__ bias,
                    float* __restrict__ partial, float* __restrict__ bsum) {
    const int t = threadIdx.x;          // 0..511
    const int b = blockIdx.x;           // 0..511
    const int g = b >> 6;               // 0..7
    const int h = b & 63;               // 0..63
    const int lane = t & 63, w = t >> 6;

    const float4* W4 = reinterpret_cast<const float4*>(W);
    const int c4   = (h << 3) + (t & 7);           // float4 col 0..511
    const int rsub = t >> 3;                       // 0..63
    const size_t base = (size_t)((g << 8) + rsub) * (IN_DIM / 4) + c4;

    float4 acc = {0.f, 0.f, 0.f, 0.f};
    #pragma unroll
    for (int k = 0; k < 4; ++k) {
        const float4 v = W4[base + (size_t)(k << 6) * (IN_DIM / 4)];
        acc.x += v.x; acc.y += v.y; acc.z += v.z; acc.w += v.w;
    }
    // merge rsub bits within the wave (lane bits 3,4,5); c4 invariant
    #pragma unroll
    for (int m = 8; m <= 32; m <<= 1) {
        acc.x += __shfl_xor(acc.x, m); acc.y += __shfl_xor(acc.y, m);
        acc.z += __shfl_xor(acc.z, m); acc.w += __shfl_xor(acc.w, m);
    }

    __shared__ float4 redA[8][8];       // [wave][col4 within slice]
    if (lane < 8) redA[w][lane] = acc;
    __syncthreads();
    if (t < 8) {                        // one thread per col4 of this slice
        float4 s = redA[0][t];
        #pragma unroll
        for (int j = 1; j < 8; ++j) {
            const float4 v = redA[j][t];
            s.x += v.x; s.y += v.y; s.z += v.z; s.w += v.w;
        }
        reinterpret_cast<float4*>(partial)[(size_t)g * (IN_DIM / 4) + (h << 3) + t] = s;
    }

    if (b == 0) {  // bias sum (concurrent with the rest)
        __shared__ float bs_red[8];
        float s = 0.f;
        #pragma unroll
        for (int k = 0; k < 4; ++k) s += bias[t + (k << 9)];
        #pragma unroll
        for (int off = 32; off; off >>= 1) s += __shfl_down(s, off);
        if (lane == 0) bs_red[w] = s;
        __syncthreads();
        if (t == 0) {
            float tot = 0.f;
            #pragma unroll
            for (int j = 0; j < 8; ++j) tot += bs_red[j];
            bsum[0] = tot;
        }
    }
}

// ---------------------------------------------------------------------------
// K2: 512 blocks x 512 threads (8 waves, 2 blocks/CU -> 4 waves/SIMD).
// Prefetch: issue partial loads AND row-0 x loads before the barrier so the
// LDS round-trip + barrier hide the first global-load latency.
// Phase 2: matvec rows [16b, 16b+16); wave w rows 16b+2w (prefetched), +1.
// ---------------------------------------------------------------------------
__global__ __launch_bounds__(512)
void reduce_matvec(const float* __restrict__ x, const float* __restrict__ partial,
                   const float* __restrict__ bsum, float* __restrict__ out) {
    __shared__ float4 wsh4[IN_DIM / 4];   // 8 KB
    __shared__ float  bs_sh;

    const int t    = threadIdx.x;          // 0..511
    const int b    = blockIdx.x;           // 0..511
    const int lane = t & 63;
    const int w    = t >> 6;               // 0..7

    // ---- issue phase-1 loads (partial[8][2048], L2-hot)
    const float4* p4 = reinterpret_cast<const float4*>(partial);
    float4 pv[DGROUPS];
    #pragma unroll
    for (int g = 0; g < DGROUPS; ++g)
        pv[g] = p4[(size_t)g * (IN_DIM / 4) + t];

    // ---- issue row-0 x loads (independent of LDS wsum)
    const float4* x4 = reinterpret_cast<const float4*>(x);
    const int r0 = (b << 4) + (w << 1);
    const size_t xb = (size_t)r0 * (IN_DIM / 4);
    float4 xv[8];
    #pragma unroll
    for (int k = 0; k < 8; ++k)
        xv[k] = x4[xb + (k << 6) + lane];

    if (t == 0) bs_sh = bsum[0];

    // ---- reduce partials into LDS wsum
    float4 acc = pv[0];
    #pragma unroll
    for (int g = 1; g < DGROUPS; ++g) {
        acc.x += pv[g].x; acc.y += pv[g].y;
        acc.z += pv[g].z; acc.w += pv[g].w;
    }
    wsh4[t] = acc;
    __syncthreads();

    // ---- phase 2: row 0 from prefetched regs, row 1 streamed in-loop
    float a0 = 0.f, a1 = 0.f;
    #pragma unroll
    for (int k = 0; k < 8; ++k) {
        const int ci = (k << 6) + lane;
        const float4 wv = wsh4[ci];
        const float4 v1 = x4[xb + 512 + ci];
        a0 += xv[k].x * wv.x + xv[k].y * wv.y + xv[k].z * wv.z + xv[k].w * wv.w;
        a1 += v1.x * wv.x + v1.y * wv.y + v1.z * wv.z + v1.w * wv.w;
    }
    #pragma unroll
    for (int off = 32; off; off >>= 1) {
        a0 += __shfl_down(a0, off);
        a1 += __shfl_down(a1, off);
    }
    if (lane == 0) {
        const float bs = bs_sh;
        *reinterpret_cast<float2*>(out + r0) =
            make_float2(SCALE2 * (a0 + bs), SCALE2 * (a1 + bs));
    }
}

extern "C" void kernel_launch(void* const* d_in, const int* in_sizes, int n_in,
                              void* d_out, int out_size, void* d_ws, size_t ws_size,
                              hipStream_t stream) {
    const float* x    = (const float*)d_in[0];   // [8192, 2048]
    const float* W    = (const float*)d_in[1];   // [2048, 2048]
    const float* bias = (const float*)d_in[2];   // [2048]
    float* out = (float*)d_out;                  // [8192]
    char*  ws  = (char*)d_ws;

    // ws layout: partial[8][2048] (64 KB) | bsum (64 B)
    float* partial = (float*)ws;
    float* bsum    = (float*)(ws + (size_t)DGROUPS * IN_DIM * sizeof(float));

    colsum_partial<<<512, 512, 0, stream>>>(W, bias, partial, bsum);
    reduce_matvec<<<BATCH / 16, 512, 0, stream>>>(x, partial, bsum, out);
}